// Round 1
// baseline (526.975 us; speedup 1.0000x reference)
//
#include <hip/hip_runtime.h>
#include <math.h>

// Problem constants (from reference)
#define B_ 16
#define T_ 4096
#define C_ 512
#define E_ 64
#define K_ 2048
#define N_ (B_*T_)          // 65536
#define ZQ_ELEMS 4194304    // B*E*T

// ws layout (bytes):
//   h_t   : [E][N] f32 @ 0          (16,777,216)
//   embT  : [E][K] f32 @ 16777216   (524,288)
//   cc    : [K]    f32 @ 17301504   (8,192)
//   qidx  : [N]    i32 @ 17309696   (262,144)
//   hist  : [K]    i32 @ 17571840   (8,192)   <- zeroed each launch
//   lossacc: [1]   f32 @ 17580032   (4)       <- zeroed each launch
#define WS_HT     0
#define WS_EMBT   16777216
#define WS_CC     17301504
#define WS_QIDX   17309696
#define WS_HIST   17571840
#define WS_LOSS   17580032

// ---------------------------------------------------------------------------
// Prep: transpose embed -> embT[e][k], and codeword norms cc[k] = ||e_k||^2
// ---------------------------------------------------------------------------
__global__ void prep_kernel(const float* __restrict__ embed,
                            float* __restrict__ embT,
                            float* __restrict__ cc) {
    __shared__ float tile[64 * 65];
    const int tid = threadIdx.x;
    const int k0 = blockIdx.x * 64;

    // Load 64 codeword rows (64 floats each), coalesced float4.
    const int k_l = tid >> 2, eq = tid & 3;
    const float4* src = (const float4*)(embed + (size_t)(k0 + k_l) * 64 + eq * 16);
#pragma unroll
    for (int j = 0; j < 4; ++j) {
        float4 v = src[j];
        int e = eq * 16 + j * 4;
        tile[k_l * 65 + e + 0] = v.x;
        tile[k_l * 65 + e + 1] = v.y;
        tile[k_l * 65 + e + 2] = v.z;
        tile[k_l * 65 + e + 3] = v.w;
    }
    __syncthreads();

    if (tid < 64) {
        float s = 0.f;
#pragma unroll 8
        for (int e = 0; e < 64; ++e) {
            float v = tile[tid * 65 + e];
            s = fmaf(v, v, s);
        }
        cc[k0 + tid] = s;
    }

    // Write transposed, coalesced along k.
    const int t_l = tid & 63;
#pragma unroll
    for (int j = 0; j < 16; ++j) {
        int e = j * 4 + (tid >> 6);
        embT[(size_t)e * K_ + k0 + t_l] = tile[t_l * 65 + e];
    }
}

// ---------------------------------------------------------------------------
// Projection: h_t[e][n] = sum_c W[e][c] * x[b][c][t] + bias[e]
// Also accumulates ||h||_F^2 into lossacc.
// Block: 256 thr, tile 128 t x 64 e, K-chunks of 32 c. Grid (T/128, B).
// ---------------------------------------------------------------------------
__global__ __launch_bounds__(256) void proj_kernel(
        const float* __restrict__ x, const float* __restrict__ W,
        const float* __restrict__ bias, float* __restrict__ h_t,
        float* __restrict__ lossacc) {
    __shared__ float xs[32 * 128];   // [c][t]
    __shared__ float wsh[32 * 68];   // [c][e], padded row 68

    const int tid = threadIdx.x;
    const int t0 = blockIdx.x * 128;
    const int b  = blockIdx.y;
    const int tq = tid & 15, eq = tid >> 4;
    const int t_base = tq * 8, e_base = eq * 4;

    float acc[4][8];
#pragma unroll
    for (int i = 0; i < 4; ++i)
#pragma unroll
        for (int j = 0; j < 8; ++j) acc[i][j] = 0.f;

    const float* xb = x + (size_t)b * C_ * T_ + t0;

    for (int c0 = 0; c0 < C_; c0 += 32) {
        // Stage x chunk [32 c][128 t], coalesced float4.
#pragma unroll
        for (int j = 0; j < 4; ++j) {
            int linear = j * 1024 + tid * 4;
            int ccc = linear >> 7, tt = linear & 127;
            float4 v = *(const float4*)(xb + (size_t)(c0 + ccc) * T_ + tt);
            *(float4*)(xs + ccc * 128 + tt) = v;
        }
        // Stage W chunk transposed [32 c][64 e].
#pragma unroll
        for (int j = 0; j < 2; ++j) {
            int linear = j * 1024 + tid * 4;
            int e = linear >> 5, ccc = linear & 31;
            float4 v = *(const float4*)(W + (size_t)e * C_ + c0 + ccc);
            wsh[(ccc + 0) * 68 + e] = v.x;
            wsh[(ccc + 1) * 68 + e] = v.y;
            wsh[(ccc + 2) * 68 + e] = v.z;
            wsh[(ccc + 3) * 68 + e] = v.w;
        }
        __syncthreads();
#pragma unroll 8
        for (int ccc = 0; ccc < 32; ++ccc) {
            float4 wv = *(const float4*)(wsh + ccc * 68 + e_base);
            float4 x0 = *(const float4*)(xs + ccc * 128 + t_base);
            float4 x1 = *(const float4*)(xs + ccc * 128 + t_base + 4);
            float xr[8] = {x0.x, x0.y, x0.z, x0.w, x1.x, x1.y, x1.z, x1.w};
            float wr[4] = {wv.x, wv.y, wv.z, wv.w};
#pragma unroll
            for (int i = 0; i < 4; ++i)
#pragma unroll
                for (int j = 0; j < 8; ++j)
                    acc[i][j] = fmaf(wr[i], xr[j], acc[i][j]);
        }
        __syncthreads();
    }

    // Bias, ||h||^2 partial, transposed store (coalesced float4 along n).
    const int n0 = b * T_ + t0;
    float hh = 0.f;
#pragma unroll
    for (int i = 0; i < 4; ++i) {
        float bv = bias[e_base + i];
#pragma unroll
        for (int j = 0; j < 8; ++j) {
            acc[i][j] += bv;
            hh = fmaf(acc[i][j], acc[i][j], hh);
        }
        float4 v0 = make_float4(acc[i][0], acc[i][1], acc[i][2], acc[i][3]);
        float4 v1 = make_float4(acc[i][4], acc[i][5], acc[i][6], acc[i][7]);
        float* dst = h_t + (size_t)(e_base + i) * N_ + n0 + t_base;
        *(float4*)(dst)     = v0;
        *(float4*)(dst + 4) = v1;
    }
#pragma unroll
    for (int m = 1; m < 64; m <<= 1) hh += __shfl_xor(hh, m, 64);
    if ((tid & 63) == 0) atomicAdd(lossacc, hh);
}

// ---------------------------------------------------------------------------
// VQ: per row n, argmin_k (cc[k] - 2 * h_n . e_k). Writes qidx, histogram,
// and accumulates sum of min-values into lossacc (d2 = ||h||^2 + minval).
// Block: 256 thr, tile 64 n x full K in chunks of 128 k. Grid N/64.
// Thread tile: 8 n x 4 k.
// ---------------------------------------------------------------------------
__global__ __launch_bounds__(256) void vq_kernel(
        const float* __restrict__ h_t, const float* __restrict__ embT,
        const float* __restrict__ cc, int* __restrict__ qidx,
        int* __restrict__ hist, float* __restrict__ lossacc) {
    __shared__ float hst[64 * 68];    // [e][n], padded row 68
    __shared__ float est[64 * 128];   // [e][k]
    __shared__ float ccs[128];

    const int tid = threadIdx.x;
    const int n0 = blockIdx.x * 64;

    // Stage h tile [64 e][64 n], coalesced along n.
#pragma unroll
    for (int j = 0; j < 4; ++j) {
        int linear = j * 1024 + tid * 4;
        int e = linear >> 6, n_l = linear & 63;
        float4 v = *(const float4*)(h_t + (size_t)e * N_ + n0 + n_l);
        *(float4*)(hst + e * 68 + n_l) = v;
    }

    const int kq = tid & 31, nq = tid >> 5;
    const int k_base = kq * 4, n_base = nq * 8;

    float minv[8];
    int   mini[8];
#pragma unroll
    for (int i = 0; i < 8; ++i) { minv[i] = 3.4e38f; mini[i] = 0; }

    for (int k0 = 0; k0 < K_; k0 += 128) {
        // Stage embT chunk [64 e][128 k], coalesced along k.
#pragma unroll
        for (int j = 0; j < 8; ++j) {
            int linear = j * 1024 + tid * 4;
            int e = linear >> 7, k_l = linear & 127;
            float4 v = *(const float4*)(embT + (size_t)e * K_ + k0 + k_l);
            *(float4*)(est + e * 128 + k_l) = v;
        }
        if (tid < 32) {
            float4 v = *(const float4*)(cc + k0 + tid * 4);
            *(float4*)(ccs + tid * 4) = v;
        }
        __syncthreads();

        float acc[8][4];
#pragma unroll
        for (int i = 0; i < 8; ++i)
#pragma unroll
            for (int j = 0; j < 4; ++j) acc[i][j] = 0.f;

#pragma unroll 8
        for (int e = 0; e < 64; ++e) {
            float4 h0 = *(const float4*)(hst + e * 68 + n_base);
            float4 h1 = *(const float4*)(hst + e * 68 + n_base + 4);
            float4 ev = *(const float4*)(est + e * 128 + k_base);
            float hr[8] = {h0.x, h0.y, h0.z, h0.w, h1.x, h1.y, h1.z, h1.w};
            float er[4] = {ev.x, ev.y, ev.z, ev.w};
#pragma unroll
            for (int i = 0; i < 8; ++i)
#pragma unroll
                for (int j = 0; j < 4; ++j)
                    acc[i][j] = fmaf(hr[i], er[j], acc[i][j]);
        }

        // Fold chunk scores into running min (ascending k => '<' keeps lowest idx)
#pragma unroll
        for (int j = 0; j < 4; ++j) {
            float cj = ccs[k_base + j];
            int kk = k0 + k_base + j;
#pragma unroll
            for (int i = 0; i < 8; ++i) {
                float d = fmaf(-2.f, acc[i][j], cj);
                if (d < minv[i]) { minv[i] = d; mini[i] = kk; }
            }
        }
        __syncthreads();
    }

    // Reduce across the 32 kq-lanes (same wave half); tie-break lowest index.
#pragma unroll
    for (int m = 1; m < 32; m <<= 1) {
#pragma unroll
        for (int i = 0; i < 8; ++i) {
            float ov = __shfl_xor(minv[i], m, 64);
            int   oi = __shfl_xor(mini[i], m, 64);
            if (ov < minv[i] || (ov == minv[i] && oi < mini[i])) {
                minv[i] = ov; mini[i] = oi;
            }
        }
    }

    if (kq == 0) {
        float s = 0.f;
#pragma unroll
        for (int i = 0; i < 8; ++i) {
            qidx[n0 + n_base + i] = mini[i];
            atomicAdd(&hist[mini[i]], 1);
            s += minv[i];
        }
        atomicAdd(lossacc, s);
    }
}

// ---------------------------------------------------------------------------
// Gather + transpose: out[b][e][t] = embed[qidx[b*T+t]][e]
// Block 256 thr, tile 64 t x 64 e. Grid (T/64, B).
// ---------------------------------------------------------------------------
__global__ void gather_kernel(const float* __restrict__ embed,
                              const int* __restrict__ qidx,
                              float* __restrict__ out) {
    __shared__ float tile[64 * 65];
    __shared__ int qs[64];
    const int tid = threadIdx.x;
    const int t0 = blockIdx.x * 64;
    const int b  = blockIdx.y;

    if (tid < 64) qs[tid] = qidx[b * T_ + t0 + tid];
    __syncthreads();

    const int t_l = tid >> 2, eq = tid & 3;
    const float4* src = (const float4*)(embed + (size_t)qs[t_l] * 64 + eq * 16);
#pragma unroll
    for (int j = 0; j < 4; ++j) {
        float4 v = src[j];
        int e = eq * 16 + j * 4;
        tile[t_l * 65 + e + 0] = v.x;
        tile[t_l * 65 + e + 1] = v.y;
        tile[t_l * 65 + e + 2] = v.z;
        tile[t_l * 65 + e + 3] = v.w;
    }
    __syncthreads();

    const int tt = tid & 63;
#pragma unroll
    for (int j = 0; j < 16; ++j) {
        int e = j * 4 + (tid >> 6);
        out[((size_t)b * 64 + e) * T_ + t0 + tt] = tile[tt * 65 + e];
    }
}

// ---------------------------------------------------------------------------
// Finalize: loss, kldiv constant, log-perplexity.
// ---------------------------------------------------------------------------
__global__ void finalize_kernel(const int* __restrict__ hist,
                                const float* __restrict__ lossacc,
                                float* __restrict__ out) {
    __shared__ float red[4];
    const int tid = threadIdx.x;
    float s = 0.f;
    for (int k = tid; k < K_; k += 256) {
        float p = (float)hist[k] * (1.f / 65536.f);
        s -= p * logf(p + 1e-10f);
    }
#pragma unroll
    for (int m = 1; m < 64; m <<= 1) s += __shfl_xor(s, m, 64);
    if ((tid & 63) == 0) red[tid >> 6] = s;
    __syncthreads();
    if (tid == 0) {
        float lp = red[0] + red[1] + red[2] + red[3];
        out[ZQ_ELEMS] = 0.25f * lossacc[0] / (float)ZQ_ELEMS;   // loss
        out[ZQ_ELEMS + 17] = lp;                                 // log_perplexity
    }
    if (tid < 16) out[ZQ_ELEMS + 1 + tid] = logf(2048.f) * 4096.f;  // kldiv_r
}

// ---------------------------------------------------------------------------
extern "C" void kernel_launch(void* const* d_in, const int* in_sizes, int n_in,
                              void* d_out, int out_size, void* d_ws, size_t ws_size,
                              hipStream_t stream) {
    const float* x      = (const float*)d_in[0];
    const float* proj_w = (const float*)d_in[1];
    const float* proj_b = (const float*)d_in[2];
    const float* embed  = (const float*)d_in[3];
    float* out = (float*)d_out;
    char* ws = (char*)d_ws;

    float* h_t    = (float*)(ws + WS_HT);
    float* embT   = (float*)(ws + WS_EMBT);
    float* cc     = (float*)(ws + WS_CC);
    int*   qidx   = (int*)(ws + WS_QIDX);
    int*   hist   = (int*)(ws + WS_HIST);
    float* lossac = (float*)(ws + WS_LOSS);

    // hist + lossacc must be zero each launch (ws is poisoned 0xAA).
    hipMemsetAsync(ws + WS_HIST, 0, K_ * sizeof(int) + sizeof(float), stream);

    prep_kernel<<<32, 256, 0, stream>>>(embed, embT, cc);
    proj_kernel<<<dim3(T_ / 128, B_), 256, 0, stream>>>(x, proj_w, proj_b, h_t, lossac);
    vq_kernel<<<N_ / 64, 256, 0, stream>>>(h_t, embT, cc, qidx, hist, lossac);
    gather_kernel<<<dim3(T_ / 64, B_), 256, 0, stream>>>(embed, qidx, out);
    finalize_kernel<<<1, 256, 0, stream>>>(hist, lossac, out);
}

// Round 2
// 350.941 us; speedup vs baseline: 1.5016x; 1.5016x over previous
//
#include <hip/hip_runtime.h>
#include <math.h>

// Problem constants (from reference)
#define B_ 16
#define T_ 4096
#define C_ 512
#define E_ 64
#define K_ 2048
#define N_ (B_*T_)          // 65536
#define ZQ_ELEMS 4194304    // B*E*T

typedef __attribute__((ext_vector_type(8))) short short8;
typedef __attribute__((ext_vector_type(4))) float f32x4;

// ws layout (bytes):
//   h_hi  : [N][E] bf16 @ 0          (8,388,608)
//   h_lo  : [N][E] bf16 @ 8388608    (8,388,608)
//   e_hi  : [K][E] bf16 @ 16777216   (262,144)
//   e_lo  : [K][E] bf16 @ 17039360   (262,144)
//   nhcc  : [K] f32 (-0.5*||e||^2) @ 17301504 (8,192)
//   qidx  : [N] i32 @ 17309696       (262,144)
//   hist  : [K] i32 @ 17571840       (8,192)   <- zeroed each launch
//   lossacc: f32 @ 17580032          (4)       <- zeroed each launch
#define WS_HHI   0
#define WS_HLO   8388608
#define WS_EHI   16777216
#define WS_ELO   17039360
#define WS_NHCC  17301504
#define WS_QIDX  17309696
#define WS_HIST  17571840
#define WS_LOSS  17580032

// round-to-nearest-even fp32 -> bf16 bits, also returns the bf16 value as f32
__device__ __forceinline__ unsigned short bf16_rne(float v, float* out_f) {
    unsigned u = __float_as_uint(v);
    unsigned r = (u + 0x7FFFu + ((u >> 16) & 1u)) >> 16;
    *out_f = __uint_as_float(r << 16);
    return (unsigned short)r;
}

// ---------------------------------------------------------------------------
// Prep: split embed into bf16 hi/lo [k][e] row-major, nhcc[k] = -0.5*||e_k||^2
// Grid 64 x 256 thr; 8 lanes per codeword row.
// ---------------------------------------------------------------------------
__global__ void prep_kernel(const float* __restrict__ embed,
                            unsigned short* __restrict__ ehi,
                            unsigned short* __restrict__ elo,
                            float* __restrict__ nhcc) {
    const int tid = threadIdx.x;
    const int row = blockIdx.x * 32 + (tid >> 3);
    const int c = (tid & 7) * 8;
    const float* src = embed + (size_t)row * 64 + c;
    short8 hv, lv;
    float s = 0.f;
#pragma unroll
    for (int j = 0; j < 8; ++j) {
        float v = src[j];
        s = fmaf(v, v, s);
        float hf; unsigned short hb = bf16_rne(v, &hf);
        float lf; unsigned short lb = bf16_rne(v - hf, &lf);
        hv[j] = (short)hb; lv[j] = (short)lb;
    }
    *(short8*)(ehi + (size_t)row * 64 + c) = hv;
    *(short8*)(elo + (size_t)row * 64 + c) = lv;
    s += __shfl_xor(s, 1, 64);
    s += __shfl_xor(s, 2, 64);
    s += __shfl_xor(s, 4, 64);
    if ((tid & 7) == 0) nhcc[row] = -0.5f * s;
}

// ---------------------------------------------------------------------------
// Projection: h[n][e] = sum_c W[e][c]*x[b][c][t] + bias[e]  (fp32 math)
// Emits h as bf16 hi/lo in [n][e] row-major (MFMA A-frag friendly).
// Accumulates ||h||_F^2 into lossacc.
// Block 256 thr, tile 128 t x 64 e. Grid (T/128, B).
// ---------------------------------------------------------------------------
__global__ __launch_bounds__(256) void proj_kernel(
        const float* __restrict__ x, const float* __restrict__ W,
        const float* __restrict__ bias,
        unsigned short* __restrict__ h_hi, unsigned short* __restrict__ h_lo,
        float* __restrict__ lossacc) {
    __shared__ float smem[8704];           // union: xs[32*128] + wsh[32*68] | tile[128*68]
    float* xs  = smem;                     // [c][t] 32x128
    float* wsh = smem + 4096;              // [c][e] 32x68

    const int tid = threadIdx.x;
    const int t0 = blockIdx.x * 128;
    const int b  = blockIdx.y;
    const int tq = tid & 15, eq = tid >> 4;
    const int t_base = tq * 8, e_base = eq * 4;

    float acc[4][8];
#pragma unroll
    for (int i = 0; i < 4; ++i)
#pragma unroll
        for (int j = 0; j < 8; ++j) acc[i][j] = 0.f;

    const float* xb = x + (size_t)b * C_ * T_ + t0;

    for (int c0 = 0; c0 < C_; c0 += 32) {
#pragma unroll
        for (int j = 0; j < 4; ++j) {
            int linear = j * 1024 + tid * 4;
            int ccc = linear >> 7, tt = linear & 127;
            float4 v = *(const float4*)(xb + (size_t)(c0 + ccc) * T_ + tt);
            *(float4*)(xs + ccc * 128 + tt) = v;
        }
#pragma unroll
        for (int j = 0; j < 2; ++j) {
            int linear = j * 1024 + tid * 4;
            int e = linear >> 5, ccc = linear & 31;
            float4 v = *(const float4*)(W + (size_t)e * C_ + c0 + ccc);
            wsh[(ccc + 0) * 68 + e] = v.x;
            wsh[(ccc + 1) * 68 + e] = v.y;
            wsh[(ccc + 2) * 68 + e] = v.z;
            wsh[(ccc + 3) * 68 + e] = v.w;
        }
        __syncthreads();
#pragma unroll 8
        for (int ccc = 0; ccc < 32; ++ccc) {
            float4 wv = *(const float4*)(wsh + ccc * 68 + e_base);
            float4 x0 = *(const float4*)(xs + ccc * 128 + t_base);
            float4 x1 = *(const float4*)(xs + ccc * 128 + t_base + 4);
            float xr[8] = {x0.x, x0.y, x0.z, x0.w, x1.x, x1.y, x1.z, x1.w};
            float wr[4] = {wv.x, wv.y, wv.z, wv.w};
#pragma unroll
            for (int i = 0; i < 4; ++i)
#pragma unroll
                for (int j = 0; j < 8; ++j)
                    acc[i][j] = fmaf(wr[i], xr[j], acc[i][j]);
        }
        __syncthreads();
    }

    // Bias + ||h||^2 partial, then park tile in LDS for the bf16-split store.
    float hh = 0.f;
#pragma unroll
    for (int i = 0; i < 4; ++i) {
        float bv = bias[e_base + i];
#pragma unroll
        for (int j = 0; j < 8; ++j) {
            acc[i][j] += bv;
            hh = fmaf(acc[i][j], acc[i][j], hh);
        }
    }
#pragma unroll
    for (int j = 0; j < 8; ++j) {
        float4 v = make_float4(acc[0][j], acc[1][j], acc[2][j], acc[3][j]);
        *(float4*)(smem + (t_base + j) * 68 + e_base) = v;
    }
#pragma unroll
    for (int m = 1; m < 64; m <<= 1) hh += __shfl_xor(hh, m, 64);
    if ((tid & 63) == 0) atomicAdd(lossacc, hh);
    __syncthreads();

    // Convert + store: 128 rows x 8 chunks of 8e; coalesced 16B/lane.
    const int n0 = b * T_ + t0;
#pragma unroll
    for (int it = 0; it < 4; ++it) {
        int idx = it * 256 + tid;
        int row = idx >> 3, ch = (idx & 7) * 8;
        short8 hv, lv;
#pragma unroll
        for (int j = 0; j < 8; ++j) {
            float v = smem[row * 68 + ch + j];
            float hf; unsigned short hb = bf16_rne(v, &hf);
            float lf; unsigned short lb = bf16_rne(v - hf, &lf);
            hv[j] = (short)hb; lv[j] = (short)lb;
        }
        size_t off = (size_t)(n0 + row) * 64 + ch;
        *(short8*)(h_hi + off) = hv;
        *(short8*)(h_lo + off) = lv;
    }
}

// ---------------------------------------------------------------------------
// VQ via bf16-split MFMA: S = h.e (3 MFMA passes), argmax of (S - 0.5*cc).
// Block 256 thr = 4 waves x 64 rows = 256 rows/block. Grid N/256.
// Wave: 4 row-tiles of 16; K in chunks of 128 staged in LDS.
// ---------------------------------------------------------------------------
__global__ __launch_bounds__(256) void vq_kernel(
        const unsigned short* __restrict__ h_hi, const unsigned short* __restrict__ h_lo,
        const unsigned short* __restrict__ ehi, const unsigned short* __restrict__ elo,
        const float* __restrict__ nhcc, int* __restrict__ qidx,
        int* __restrict__ hist, float* __restrict__ lossacc) {
    __shared__ unsigned short es_hi[128 * 72];   // [k][e] pad 72
    __shared__ unsigned short es_lo[128 * 72];
    __shared__ float ccs[128];

    const int tid = threadIdx.x;
    const int wave = tid >> 6, lane = tid & 63;
    const int row16 = lane & 15, quad = lane >> 4;
    const int nw = blockIdx.x * 256 + wave * 64;

    // A fragments: 4 row-tiles x 2 k-steps, hi+lo. Held in regs all kernel.
    short8 a_hi[4][2], a_lo[4][2];
#pragma unroll
    for (int rt = 0; rt < 4; ++rt) {
#pragma unroll
        for (int ks = 0; ks < 2; ++ks) {
            size_t off = (size_t)(nw + rt * 16 + row16) * 64 + ks * 32 + quad * 8;
            a_hi[rt][ks] = *(const short8*)(h_hi + off);
            a_lo[rt][ks] = *(const short8*)(h_lo + off);
        }
    }

    float vmax[4][4];
    int   vidx[4][4];
#pragma unroll
    for (int rt = 0; rt < 4; ++rt)
#pragma unroll
        for (int rg = 0; rg < 4; ++rg) { vmax[rt][rg] = -3.4e38f; vidx[rt][rg] = 0; }

    for (int k0 = 0; k0 < K_; k0 += 128) {
#pragma unroll
        for (int it = 0; it < 4; ++it) {
            int idx = it * 256 + tid;
            int r = idx >> 3, c8 = (idx & 7) * 8;
            *(short8*)(es_hi + r * 72 + c8) = *(const short8*)(ehi + (size_t)(k0 + r) * 64 + c8);
            *(short8*)(es_lo + r * 72 + c8) = *(const short8*)(elo + (size_t)(k0 + r) * 64 + c8);
        }
        if (tid < 32) *(f32x4*)(ccs + tid * 4) = *(const f32x4*)(nhcc + k0 + tid * 4);
        __syncthreads();

#pragma unroll
        for (int kt = 0; kt < 8; ++kt) {
            const int colbase = kt * 16;
            float ci = ccs[colbase + row16];
            const unsigned short* bp = es_hi + (colbase + row16) * 72 + quad * 8;
            const unsigned short* bq = es_lo + (colbase + row16) * 72 + quad * 8;
            short8 bh0 = *(const short8*)(bp);
            short8 bh1 = *(const short8*)(bp + 32);
            short8 bl0 = *(const short8*)(bq);
            short8 bl1 = *(const short8*)(bq + 32);
            const int kk = k0 + colbase + row16;
#pragma unroll
            for (int rt = 0; rt < 4; ++rt) {
                f32x4 acc = {ci, ci, ci, ci};
                acc = __builtin_amdgcn_mfma_f32_16x16x32_bf16(a_hi[rt][0], bh0, acc, 0, 0, 0);
                acc = __builtin_amdgcn_mfma_f32_16x16x32_bf16(a_hi[rt][1], bh1, acc, 0, 0, 0);
                acc = __builtin_amdgcn_mfma_f32_16x16x32_bf16(a_lo[rt][0], bh0, acc, 0, 0, 0);
                acc = __builtin_amdgcn_mfma_f32_16x16x32_bf16(a_lo[rt][1], bh1, acc, 0, 0, 0);
                acc = __builtin_amdgcn_mfma_f32_16x16x32_bf16(a_hi[rt][0], bl0, acc, 0, 0, 0);
                acc = __builtin_amdgcn_mfma_f32_16x16x32_bf16(a_hi[rt][1], bl1, acc, 0, 0, 0);
#pragma unroll
                for (int rg = 0; rg < 4; ++rg) {
                    float v = acc[rg];
                    if (v > vmax[rt][rg]) { vmax[rt][rg] = v; vidx[rt][rg] = kk; }
                }
            }
        }
        __syncthreads();
    }

    // Reduce across the 16 col-lanes; tie -> lowest index. Then emit.
    float s = 0.f;
#pragma unroll
    for (int rt = 0; rt < 4; ++rt) {
#pragma unroll
        for (int rg = 0; rg < 4; ++rg) {
            float v = vmax[rt][rg];
            int ix = vidx[rt][rg];
#pragma unroll
            for (int m = 1; m < 16; m <<= 1) {
                float ov = __shfl_xor(v, m, 64);
                int   oi = __shfl_xor(ix, m, 64);
                if (ov > v || (ov == v && oi < ix)) { v = ov; ix = oi; }
            }
            if (row16 == 0) {
                int rown = nw + rt * 16 + quad * 4 + rg;
                qidx[rown] = ix;
                atomicAdd(&hist[ix], 1);
                s += v;
            }
        }
    }
    s += __shfl_xor(s, 16, 64);
    s += __shfl_xor(s, 32, 64);
    if (lane == 0) atomicAdd(lossacc, -2.f * s);   // sum of min (cc - 2S) terms
}

// ---------------------------------------------------------------------------
// Gather + transpose: out[b][e][t] = embed[qidx[b*T+t]][e]  (fp32 exact)
// ---------------------------------------------------------------------------
__global__ void gather_kernel(const float* __restrict__ embed,
                              const int* __restrict__ qidx,
                              float* __restrict__ out) {
    __shared__ float tile[64 * 65];
    __shared__ int qs[64];
    const int tid = threadIdx.x;
    const int t0 = blockIdx.x * 64;
    const int b  = blockIdx.y;

    if (tid < 64) qs[tid] = qidx[b * T_ + t0 + tid];
    __syncthreads();

    const int t_l = tid >> 2, eq = tid & 3;
    const float4* src = (const float4*)(embed + (size_t)qs[t_l] * 64 + eq * 16);
#pragma unroll
    for (int j = 0; j < 4; ++j) {
        float4 v = src[j];
        int e = eq * 16 + j * 4;
        tile[t_l * 65 + e + 0] = v.x;
        tile[t_l * 65 + e + 1] = v.y;
        tile[t_l * 65 + e + 2] = v.z;
        tile[t_l * 65 + e + 3] = v.w;
    }
    __syncthreads();

    const int tt = tid & 63;
#pragma unroll
    for (int j = 0; j < 16; ++j) {
        int e = j * 4 + (tid >> 6);
        out[((size_t)b * 64 + e) * T_ + t0 + tt] = tile[tt * 65 + e];
    }
}

// ---------------------------------------------------------------------------
// Finalize: loss, kldiv constant, log-perplexity.
// ---------------------------------------------------------------------------
__global__ void finalize_kernel(const int* __restrict__ hist,
                                const float* __restrict__ lossacc,
                                float* __restrict__ out) {
    __shared__ float red[4];
    const int tid = threadIdx.x;
    float s = 0.f;
    for (int k = tid; k < K_; k += 256) {
        float p = (float)hist[k] * (1.f / 65536.f);
        s -= p * logf(p + 1e-10f);
    }
#pragma unroll
    for (int m = 1; m < 64; m <<= 1) s += __shfl_xor(s, m, 64);
    if ((tid & 63) == 0) red[tid >> 6] = s;
    __syncthreads();
    if (tid == 0) {
        float lp = red[0] + red[1] + red[2] + red[3];
        out[ZQ_ELEMS] = 0.25f * lossacc[0] / (float)ZQ_ELEMS;    // loss
        out[ZQ_ELEMS + 17] = lp;                                  // log_perplexity
    }
    if (tid < 16) out[ZQ_ELEMS + 1 + tid] = logf(2048.f) * 4096.f;  // kldiv_r
}

// ---------------------------------------------------------------------------
extern "C" void kernel_launch(void* const* d_in, const int* in_sizes, int n_in,
                              void* d_out, int out_size, void* d_ws, size_t ws_size,
                              hipStream_t stream) {
    const float* x      = (const float*)d_in[0];
    const float* proj_w = (const float*)d_in[1];
    const float* proj_b = (const float*)d_in[2];
    const float* embed  = (const float*)d_in[3];
    float* out = (float*)d_out;
    char* ws = (char*)d_ws;

    unsigned short* h_hi = (unsigned short*)(ws + WS_HHI);
    unsigned short* h_lo = (unsigned short*)(ws + WS_HLO);
    unsigned short* e_hi = (unsigned short*)(ws + WS_EHI);
    unsigned short* e_lo = (unsigned short*)(ws + WS_ELO);
    float* nhcc   = (float*)(ws + WS_NHCC);
    int*   qidx   = (int*)(ws + WS_QIDX);
    int*   hist   = (int*)(ws + WS_HIST);
    float* lossac = (float*)(ws + WS_LOSS);

    // hist + lossacc must be zero each launch (ws is poisoned 0xAA).
    hipMemsetAsync(ws + WS_HIST, 0, K_ * sizeof(int) + sizeof(float), stream);

    prep_kernel<<<64, 256, 0, stream>>>(embed, e_hi, e_lo, nhcc);
    proj_kernel<<<dim3(T_ / 128, B_), 256, 0, stream>>>(x, proj_w, proj_b, h_hi, h_lo, lossac);
    vq_kernel<<<N_ / 256, 256, 0, stream>>>(h_hi, h_lo, e_hi, e_lo, nhcc, qidx, hist, lossac);
    gather_kernel<<<dim3(T_ / 64, B_), 256, 0, stream>>>(embed, qidx, out);
    finalize_kernel<<<1, 256, 0, stream>>>(hist, lossac, out);
}